// Round 5
// baseline (414.698 us; speedup 1.0000x reference)
//
#include <hip/hip_runtime.h>

// GAT 2-layer, N=100K, DIM=256, HID=16, NCLS=64, E=3.2M (+N self loops).
//  - CSR build: two-level bucketed counting sort (p0 hist, scanb, p1 coarse
//    scatter LDS-staged, p2 per-bucket fine sort) -> no random 4B scatter.
//  - h1: 16 lanes/node-pair slice, 2 nodes/thread (halves LDS instr/node),
//    x direct-global coalesced, W1 in LDS transposed (stride 65 f4),
//    butterfly transpose-reduce -> lane j holds h[j].
//  - agg: 16 lanes/node as (eq 0..3 edge-slot) x (jq 0..3 float4-of-j).
//    float4 h-row gathers (4x fewer VMEM instrs vs scalar), no-max softmax
//    (max cancels algebraically), fixed 16-edge chunks fully unrolled,
//    eq-reduction via shfl_xor(4,8).
//  - layer2 fused to the end: (sum a*h_relu)@W2 == (sum a*h_relu)@W2 row in
//    LDS -> in-block @W2 + log_softmax (no h2/agg2 global round-trip).

#define DIM 256
#define HID 16
#define NCLS 64
#define NEG 0.2f
#define P1_CHUNK 4096

__device__ __forceinline__ float lrelu(float v) { return v >= 0.f ? v : NEG * v; }

// Also zeroes bkt_cnt (replaces a separate memset dispatch).
__global__ void vsd_kernel(const float* __restrict__ W2, const float* __restrict__ as2,
                           const float* __restrict__ ad2, float* __restrict__ vsd,
                           int* __restrict__ bkt_cnt) {
    int t = threadIdx.x;
    bkt_cnt[t] = 0;  // 512 threads
    if (t < 32) {
        int j = t & 15;
        const float* a = (t < 16) ? as2 : ad2;
        float s = 0.f;
        for (int c = 0; c < NCLS; ++c) s += W2[j * NCLS + c] * a[c];
        vsd[t] = s;
    }
}

// ---- CSR build ------------------------------------------------------------

__global__ __launch_bounds__(256) void p0_hist(const int* __restrict__ dst, int E,
                                               int* __restrict__ bkt_cnt) {
    __shared__ int hist[512];
    int t = threadIdx.x;
    for (int i = t; i < 512; i += 256) hist[i] = 0;
    __syncthreads();
    int base = blockIdx.x * P1_CHUNK;
    for (int k = 0; k < 16; ++k) {
        int idx = base + k * 256 + t;
        if (idx < E) atomicAdd(&hist[dst[idx] >> 8], 1);
    }
    __syncthreads();
    for (int i = t; i < 512; i += 256)
        if (hist[i]) atomicAdd(&bkt_cnt[i], hist[i]);
}

__global__ void scanb(const int* __restrict__ bkt_cnt, int* __restrict__ bkt_base,
                      int* __restrict__ bkt_cur, int nb) {
    __shared__ int lds[512];
    int t = threadIdx.x;
    int v = (t < nb) ? bkt_cnt[t] : 0;
    lds[t] = v;
    __syncthreads();
    for (int o = 1; o < 512; o <<= 1) {
        int x = (t >= o) ? lds[t - o] : 0;
        __syncthreads();
        lds[t] += x;
        __syncthreads();
    }
    if (t < nb) {
        int e = lds[t] - v;
        bkt_base[t] = e;
        bkt_cur[t] = e;
    }
}

__global__ __launch_bounds__(256) void p1_scatter(const int* __restrict__ ei, int E,
                                                  int* __restrict__ bkt_cur,
                                                  int* __restrict__ coarse) {
    __shared__ int hist[512];
    __shared__ int recs[P1_CHUNK];
    __shared__ unsigned short bkts[P1_CHUNK];
    int t = threadIdx.x;
    int base = blockIdx.x * P1_CHUNK;
    for (int i = t; i < 512; i += 256) hist[i] = 0;
    __syncthreads();
    for (int k = 0; k < 16; ++k) {
        int idx = base + k * 256 + t;
        int li = k * 256 + t;
        if (idx < E) {
            int s = ei[idx];
            int d = ei[E + idx];
            int bk = d >> 8;
            recs[li] = (s << 8) | (d & 255);
            bkts[li] = (unsigned short)bk;
            atomicAdd(&hist[bk], 1);
        } else {
            bkts[li] = 0xFFFF;
        }
    }
    __syncthreads();
    for (int b = t; b < 512; b += 256) {
        int c = hist[b];
        hist[b] = c ? atomicAdd(&bkt_cur[b], c) : 0;
    }
    __syncthreads();
    for (int k = 0; k < 16; ++k) {
        int li = k * 256 + t;
        unsigned short bk = bkts[li];
        if (bk != 0xFFFF) {
            int pos = atomicAdd(&hist[bk], 1);
            coarse[pos] = recs[li];
        }
    }
}

__global__ __launch_bounds__(256) void p2_fine(const int* __restrict__ coarse,
                                               const int* __restrict__ bkt_base,
                                               const int* __restrict__ bkt_cnt,
                                               int* __restrict__ csr, int* __restrict__ row_ptr,
                                               int* __restrict__ deg, int n) {
    __shared__ int cnt[256];
    __shared__ int off[256];
    int b = blockIdx.x;
    int t = threadIdx.x;
    cnt[t] = 0;
    __syncthreads();
    int base = bkt_base[b];
    int m = bkt_cnt[b];
    for (int i = t; i < m; i += 256) atomicAdd(&cnt[coarse[base + i] & 255], 1);
    __syncthreads();
    int v = cnt[t];
    off[t] = v;
    __syncthreads();
    for (int o = 1; o < 256; o <<= 1) {
        int x = (t >= o) ? off[t - o] : 0;
        __syncthreads();
        off[t] += x;
        __syncthreads();
    }
    int excl = off[t] - v;
    int node = b * 256 + t;
    if (node < n) {
        row_ptr[node] = base + excl;
        deg[node] = v;
    }
    __syncthreads();
    cnt[t] = base + excl;  // reuse as cursor
    __syncthreads();
    for (int i = t; i < m; i += 256) {
        int rec = coarse[base + i];
        int pos = atomicAdd(&cnt[rec & 255], 1);
        csr[pos] = rec >> 8;
    }
}

// ---- compute --------------------------------------------------------------

// 256 threads = 16 groups x 2 nodes = 32 nodes/block. Lane owns k-slice;
// x direct-global; W1 in LDS transposed wT[j][k] (stride 65 f4); two
// butterfly transpose-reduces leave lane j holding h[node][j].
__global__ __launch_bounds__(256) void h1_kernel(
    const float* __restrict__ x, const float* __restrict__ W1,
    const float* __restrict__ asw, const float* __restrict__ adw,
    float* __restrict__ h1, float* __restrict__ as1, float* __restrict__ ad1, int n) {
    __shared__ float wT[HID * 260];   // wT[j][k], row stride 260 floats (65 f4)
    __shared__ float asv[HID], adv[HID];
    int t = threadIdx.x;
    {
        int jj = t & 15, kk = t >> 4;
#pragma unroll
        for (int r = 0; r < 16; ++r) {
            int k = kk + 16 * r;
            wT[jj * 260 + k] = W1[k * HID + jj];
        }
    }
    if (t < HID) { asv[t] = asw[t]; adv[t] = adw[t]; }
    __syncthreads();
    int node0 = blockIdx.x * 32 + (t >> 4) * 2;
    int node1 = node0 + 1;
    int lj = t & 15;
    if (node0 >= n) return;
    bool has1 = node1 < n;
    const float4* x4a = (const float4*)(x + (size_t)node0 * DIM);
    const float4* x4b = (const float4*)(x + (size_t)(has1 ? node1 : node0) * DIM);
    const float4* wT4 = (const float4*)wT;
    float acc0[16], acc1[16];
#pragma unroll
    for (int j = 0; j < 16; ++j) { acc0[j] = 0.f; acc1[j] = 0.f; }
#pragma unroll
    for (int s = 0; s < 4; ++s) {
        int kf = s * 16 + lj;
        float4 xa = x4a[kf];
        float4 xb = x4b[kf];
#pragma unroll
        for (int jj = 0; jj < 16; ++jj) {
            float4 wv = wT4[jj * 65 + kf];
            acc0[jj] += xa.x * wv.x + xa.y * wv.y + xa.z * wv.z + xa.w * wv.w;
            acc1[jj] += xb.x * wv.x + xb.y * wv.y + xb.z * wv.z + xb.w * wv.w;
        }
    }
    // two butterfly transpose-reduces (compile-time register indices)
#pragma unroll
    for (int which = 0; which < 2; ++which) {
        float* acc = which ? acc1 : acc0;
        float a8[8], a4[4], a2[2], hv;
        {
            bool p = lj & 1;
#pragma unroll
            for (int j = 0; j < 8; ++j) {
                float keep = p ? acc[2 * j + 1] : acc[2 * j];
                float send = p ? acc[2 * j] : acc[2 * j + 1];
                a8[j] = keep + __shfl_xor(send, 1, 64);
            }
        }
        {
            bool p = lj & 2;
#pragma unroll
            for (int j = 0; j < 4; ++j) {
                float keep = p ? a8[2 * j + 1] : a8[2 * j];
                float send = p ? a8[2 * j] : a8[2 * j + 1];
                a4[j] = keep + __shfl_xor(send, 2, 64);
            }
        }
        {
            bool p = lj & 4;
#pragma unroll
            for (int j = 0; j < 2; ++j) {
                float keep = p ? a4[2 * j + 1] : a4[2 * j];
                float send = p ? a4[2 * j] : a4[2 * j + 1];
                a2[j] = keep + __shfl_xor(send, 4, 64);
            }
        }
        {
            bool p = lj & 8;
            float keep = p ? a2[1] : a2[0];
            float send = p ? a2[0] : a2[1];
            hv = keep + __shfl_xor(send, 8, 64);
        }
        int node = which ? node1 : node0;
        if (which == 0 || has1) {
            h1[(size_t)node * HID + lj] = hv;
            float t1 = hv * asv[lj];
            float t2 = hv * adv[lj];
#pragma unroll
            for (int m = 1; m < 16; m <<= 1) {
                t1 += __shfl_xor(t1, m, 64);
                t2 += __shfl_xor(t2, m, 64);
            }
            if (lj == 0) { as1[node] = t1; ad1[node] = t2; }
        }
    }
}

// Aggregation core: 16 lanes/node = (eq 0..3) x (jq 0..3). Returns the
// softmax-weighted sum (float4 over j-block jq) and denom, valid on ALL lanes.
__device__ __forceinline__ void agg_core(
    const float4* __restrict__ h4, const float* __restrict__ as, float adi,
    int node, int start, int cnt, const int* __restrict__ csr,
    int lg, int eq, int jq, int gbase, float4& accv, float& denomv) {
    float w0 = __expf(lrelu(as[node] + adi));
    float sel = (eq == 0) ? 1.f : 0.f;
    float w0s = w0 * sel;
    float4 hself = h4[(size_t)node * 4 + jq];
    float4 acc = make_float4(w0s * hself.x, w0s * hself.y, w0s * hself.z, w0s * hself.w);
    float denom = w0s;
    for (int q0 = 0; q0 < cnt; q0 += 16) {
        int myq = q0 + lg;
        int sv = 0;
        float wv = 0.f;
        if (myq < cnt) {
            sv = csr[start + myq];
            wv = __expf(lrelu(as[sv] + adi));
        }
#pragma unroll
        for (int r = 0; r < 4; ++r) {
            int lane = gbase + r * 4 + eq;
            int s = __shfl(sv, lane, 64);
            float w = __shfl(wv, lane, 64);
            denom += w;
            float4 hv = h4[(size_t)s * 4 + jq];
            acc.x += w * hv.x;
            acc.y += w * hv.y;
            acc.z += w * hv.z;
            acc.w += w * hv.w;
        }
    }
    // reduce across eq (bits 2,3 of lane-in-group)
#pragma unroll
    for (int m = 4; m <= 8; m <<= 1) {
        acc.x += __shfl_xor(acc.x, m, 64);
        acc.y += __shfl_xor(acc.y, m, 64);
        acc.z += __shfl_xor(acc.z, m, 64);
        acc.w += __shfl_xor(acc.w, m, 64);
        denom += __shfl_xor(denom, m, 64);
    }
    accv = acc;
    denomv = denom;
}

// Layer-1 aggregation: +b1, relu, write hrelu, alpha2 logits via vsd.
__global__ __launch_bounds__(256) void agg1_kernel(
    const float* __restrict__ h, const float* __restrict__ as, const float* __restrict__ ad,
    const int* __restrict__ row_ptr, const int* __restrict__ deg, const int* __restrict__ csr,
    const float* __restrict__ bias, const float* __restrict__ vsd,
    float* __restrict__ outfeat, float* __restrict__ as_out, float* __restrict__ ad_out,
    int n) {
    int t = threadIdx.x;
    int node = blockIdx.x * 16 + (t >> 4);
    if (node >= n) return;
    int lg = t & 15, jq = lg & 3, eq = lg >> 2, gbase = t & 48;
    float adi = ad[node];
    float4 acc;
    float denom;
    agg_core((const float4*)h, as, adi, node, row_ptr[node], deg[node], csr,
             lg, eq, jq, gbase, acc, denom);
    float inv = 1.f / denom;
    float4 b4 = ((const float4*)bias)[jq];
    float4 val;
    val.x = fmaxf(acc.x * inv + b4.x, 0.f);
    val.y = fmaxf(acc.y * inv + b4.y, 0.f);
    val.z = fmaxf(acc.z * inv + b4.z, 0.f);
    val.w = fmaxf(acc.w * inv + b4.w, 0.f);
    if (eq == 0) ((float4*)outfeat)[(size_t)node * 4 + jq] = val;
    float4 vs = ((const float4*)vsd)[jq];
    float4 vd = ((const float4*)vsd)[4 + jq];
    float t1 = val.x * vs.x + val.y * vs.y + val.z * vs.z + val.w * vs.w;
    float t2 = val.x * vd.x + val.y * vd.y + val.z * vd.z + val.w * vd.w;
#pragma unroll
    for (int m = 1; m <= 2; m <<= 1) {
        t1 += __shfl_xor(t1, m, 64);
        t2 += __shfl_xor(t2, m, 64);
    }
    if (lg == 0) { as_out[node] = t1; ad_out[node] = t2; }
}

// Layer-2 aggregation fused with @W2 + b2 + log_softmax (no agg2 round-trip).
__global__ __launch_bounds__(256) void agg2_final_kernel(
    const float* __restrict__ h, const float* __restrict__ as, const float* __restrict__ ad,
    const int* __restrict__ row_ptr, const int* __restrict__ deg, const int* __restrict__ csr,
    const float* __restrict__ W2, const float* __restrict__ b2,
    float* __restrict__ out, int n) {
    __shared__ float a2s[16 * HID];       // staged agg rows for this block
    __shared__ float w2s[HID * NCLS];     // 4KB
    __shared__ float b2s[NCLS];
    int t = threadIdx.x;
    for (int i = t; i < HID * NCLS; i += 256) w2s[i] = W2[i];
    if (t < NCLS) b2s[t] = b2[t];
    int g = t >> 4;
    int node = blockIdx.x * 16 + g;
    int lg = t & 15, jq = lg & 3, eq = lg >> 2, gbase = t & 48;
    if (node < n) {
        float adi = ad[node];
        float4 acc;
        float denom;
        agg_core((const float4*)h, as, adi, node, row_ptr[node], deg[node], csr,
                 lg, eq, jq, gbase, acc, denom);
        float inv = 1.f / denom;
        if (eq == 0) {
            float4 val = make_float4(acc.x * inv, acc.y * inv, acc.z * inv, acc.w * inv);
            *(float4*)&a2s[g * HID + jq * 4] = val;
        }
    }
    __syncthreads();
    int wv = t >> 6;   // wave id 0..3
    int c = t & 63;
#pragma unroll
    for (int i = 0; i < 4; ++i) {
        int nl = i * 4 + wv;
        int gn = blockIdx.x * 16 + nl;
        if (gn >= n) continue;
        const float* ar = &a2s[nl * HID];
        float v = b2s[c];
#pragma unroll
        for (int j = 0; j < HID; ++j) v += ar[j] * w2s[j * NCLS + c];
        float mx = v;
#pragma unroll
        for (int off = 1; off < 64; off <<= 1) mx = fmaxf(mx, __shfl_xor(mx, off, 64));
        float ex = __expf(v - mx);
        float s = ex;
#pragma unroll
        for (int off = 1; off < 64; off <<= 1) s += __shfl_xor(s, off, 64);
        out[(size_t)gn * NCLS + c] = (v - mx) - __logf(s);
    }
}

extern "C" void kernel_launch(void* const* d_in, const int* in_sizes, int n_in,
                              void* d_out, int out_size, void* d_ws, size_t ws_size,
                              hipStream_t stream) {
    const float* x    = (const float*)d_in[0];
    const int*   ei   = (const int*)d_in[1];  // [2,E]: [0..E)=src, [E..2E)=dst
    const float* W1   = (const float*)d_in[2];
    const float* a_s1 = (const float*)d_in[3];
    const float* a_d1 = (const float*)d_in[4];
    const float* b1   = (const float*)d_in[5];
    const float* W2   = (const float*)d_in[6];
    const float* a_s2 = (const float*)d_in[7];
    const float* a_d2 = (const float*)d_in[8];
    const float* b2   = (const float*)d_in[9];
    float* out = (float*)d_out;

    const int N = in_sizes[0] / DIM;
    const int E = in_sizes[1] / 2;
    const int NB = (N + 255) >> 8;  // buckets of 256 dst nodes (<= 512)

    char* p = (char*)d_ws;
    auto alloc = [&](size_t bytes) {
        char* r = p;
        p += (bytes + 255) & ~(size_t)255;
        return r;
    };
    int*   bkt_cnt  = (int*)alloc(512 * 4);
    int*   bkt_base = (int*)alloc(512 * 4);
    int*   bkt_cur  = (int*)alloc(512 * 4);
    int*   coarse   = (int*)alloc((size_t)E * 4);
    int*   csr      = (int*)alloc((size_t)E * 4);
    int*   row_ptr  = (int*)alloc((size_t)N * 4);
    int*   deg      = (int*)alloc((size_t)N * 4);
    float* as1      = (float*)alloc((size_t)N * 4);
    float* ad1      = (float*)alloc((size_t)N * 4);
    float* as2      = (float*)alloc((size_t)N * 4);
    float* ad2      = (float*)alloc((size_t)N * 4);
    float* vsd      = (float*)alloc(32 * 4);
    // coarse is dead after p2_fine; h1/hrelu alias onto it (2*N*HID*4 == E*4).
    float* h1    = (float*)coarse;
    float* hrelu = h1 + (size_t)N * HID;

    const int nblkE = (E + P1_CHUNK - 1) / P1_CHUNK;

    vsd_kernel<<<1, 512, 0, stream>>>(W2, a_s2, a_d2, vsd, bkt_cnt);
    p0_hist<<<nblkE, 256, 0, stream>>>(ei + E, E, bkt_cnt);
    scanb<<<1, 512, 0, stream>>>(bkt_cnt, bkt_base, bkt_cur, NB);
    p1_scatter<<<nblkE, 256, 0, stream>>>(ei, E, bkt_cur, coarse);
    p2_fine<<<NB, 256, 0, stream>>>(coarse, bkt_base, bkt_cnt, csr, row_ptr, deg, N);
    h1_kernel<<<(N + 31) / 32, 256, 0, stream>>>(x, W1, a_s1, a_d1, h1, as1, ad1, N);
    agg1_kernel<<<(N + 15) / 16, 256, 0, stream>>>(h1, as1, ad1, row_ptr, deg, csr,
                                                   b1, vsd, hrelu, as2, ad2, N);
    agg2_final_kernel<<<(N + 15) / 16, 256, 0, stream>>>(hrelu, as2, ad2, row_ptr, deg, csr,
                                                         W2, b2, out, N);
}

// Round 6
// 369.234 us; speedup vs baseline: 1.1231x; 1.1231x over previous
//
#include <hip/hip_runtime.h>
#include <hip/hip_fp16.h>

// GAT 2-layer, N=100K, DIM=256, HID=16, NCLS=64, E=3.2M (+N self loops).
//  - CSR build: two-level bucketed counting sort (p0 hist, scanb, p1 coarse
//    scatter LDS-staged, p2 per-bucket fine sort) -> no random 4B scatter.
//  - h1: 16 lanes/node, lane owns k-slice, x direct-global coalesced, W1 in
//    LDS transposed (stride 65 f4), butterfly transpose-reduce. 1 node/thread
//    (R5's 2-node variant blew VGPR->156, occupancy 10%, +40us: reverted).
//    h rows stored as PACKED HALF8 (32B/row) for the agg gathers.
//  - agg: 16 lanes/node = (eq 0..7 edge-slot) x (jq 0..1 half-row). Each lane
//    gathers uint4 (16B = 8 halves) -> half the bytes + half the VMEM instrs
//    vs fp32 float4 scheme. No-max softmax (max cancels algebraically).
//    fp16 storage rel-err ~5e-4 -> output absmax impact ~1e-3 (budget 0.106).
//  - layer2 fused: (sum a*h_relu)@W2 == sum a*(h_relu@W2); @W2 + b2 +
//    log_softmax in-block via LDS staging (no h2/agg2 global round-trip).

#define DIM 256
#define HID 16
#define NCLS 64
#define NEG 0.2f
#define P1_CHUNK 4096

__device__ __forceinline__ float lrelu(float v) { return v >= 0.f ? v : NEG * v; }

__device__ __forceinline__ uint4 pack_half8(const float* v) {
    __half2 p0 = __floats2half2_rn(v[0], v[1]);
    __half2 p1 = __floats2half2_rn(v[2], v[3]);
    __half2 p2 = __floats2half2_rn(v[4], v[5]);
    __half2 p3 = __floats2half2_rn(v[6], v[7]);
    return make_uint4(*(unsigned*)&p0, *(unsigned*)&p1, *(unsigned*)&p2, *(unsigned*)&p3);
}

__device__ __forceinline__ void unpack_half8(uint4 u, float* f) {
    float2 f0 = __half22float2(*(__half2*)&u.x);
    float2 f1 = __half22float2(*(__half2*)&u.y);
    float2 f2 = __half22float2(*(__half2*)&u.z);
    float2 f3 = __half22float2(*(__half2*)&u.w);
    f[0] = f0.x; f[1] = f0.y; f[2] = f1.x; f[3] = f1.y;
    f[4] = f2.x; f[5] = f2.y; f[6] = f3.x; f[7] = f3.y;
}

// Also zeroes bkt_cnt (replaces a separate memset dispatch).
__global__ void vsd_kernel(const float* __restrict__ W2, const float* __restrict__ as2,
                           const float* __restrict__ ad2, float* __restrict__ vsd,
                           int* __restrict__ bkt_cnt) {
    int t = threadIdx.x;
    bkt_cnt[t] = 0;  // 512 threads
    if (t < 32) {
        int j = t & 15;
        const float* a = (t < 16) ? as2 : ad2;
        float s = 0.f;
        for (int c = 0; c < NCLS; ++c) s += W2[j * NCLS + c] * a[c];
        vsd[t] = s;
    }
}

// ---- CSR build ------------------------------------------------------------

__global__ __launch_bounds__(256) void p0_hist(const int* __restrict__ dst, int E,
                                               int* __restrict__ bkt_cnt) {
    __shared__ int hist[512];
    int t = threadIdx.x;
    for (int i = t; i < 512; i += 256) hist[i] = 0;
    __syncthreads();
    int base = blockIdx.x * P1_CHUNK;
    for (int k = 0; k < 16; ++k) {
        int idx = base + k * 256 + t;
        if (idx < E) atomicAdd(&hist[dst[idx] >> 8], 1);
    }
    __syncthreads();
    for (int i = t; i < 512; i += 256)
        if (hist[i]) atomicAdd(&bkt_cnt[i], hist[i]);
}

__global__ void scanb(const int* __restrict__ bkt_cnt, int* __restrict__ bkt_base,
                      int* __restrict__ bkt_cur, int nb) {
    __shared__ int lds[512];
    int t = threadIdx.x;
    int v = (t < nb) ? bkt_cnt[t] : 0;
    lds[t] = v;
    __syncthreads();
    for (int o = 1; o < 512; o <<= 1) {
        int x = (t >= o) ? lds[t - o] : 0;
        __syncthreads();
        lds[t] += x;
        __syncthreads();
    }
    if (t < nb) {
        int e = lds[t] - v;
        bkt_base[t] = e;
        bkt_cur[t] = e;
    }
}

__global__ __launch_bounds__(256) void p1_scatter(const int* __restrict__ ei, int E,
                                                  int* __restrict__ bkt_cur,
                                                  int* __restrict__ coarse) {
    __shared__ int hist[512];
    __shared__ int recs[P1_CHUNK];
    __shared__ unsigned short bkts[P1_CHUNK];
    int t = threadIdx.x;
    int base = blockIdx.x * P1_CHUNK;
    for (int i = t; i < 512; i += 256) hist[i] = 0;
    __syncthreads();
    for (int k = 0; k < 16; ++k) {
        int idx = base + k * 256 + t;
        int li = k * 256 + t;
        if (idx < E) {
            int s = ei[idx];
            int d = ei[E + idx];
            int bk = d >> 8;
            recs[li] = (s << 8) | (d & 255);
            bkts[li] = (unsigned short)bk;
            atomicAdd(&hist[bk], 1);
        } else {
            bkts[li] = 0xFFFF;
        }
    }
    __syncthreads();
    for (int b = t; b < 512; b += 256) {
        int c = hist[b];
        hist[b] = c ? atomicAdd(&bkt_cur[b], c) : 0;
    }
    __syncthreads();
    for (int k = 0; k < 16; ++k) {
        int li = k * 256 + t;
        unsigned short bk = bkts[li];
        if (bk != 0xFFFF) {
            int pos = atomicAdd(&hist[bk], 1);
            coarse[pos] = recs[li];
        }
    }
}

__global__ __launch_bounds__(256) void p2_fine(const int* __restrict__ coarse,
                                               const int* __restrict__ bkt_base,
                                               const int* __restrict__ bkt_cnt,
                                               int* __restrict__ csr, int* __restrict__ row_ptr,
                                               int* __restrict__ deg, int n) {
    __shared__ int cnt[256];
    __shared__ int off[256];
    int b = blockIdx.x;
    int t = threadIdx.x;
    cnt[t] = 0;
    __syncthreads();
    int base = bkt_base[b];
    int m = bkt_cnt[b];
    for (int i = t; i < m; i += 256) atomicAdd(&cnt[coarse[base + i] & 255], 1);
    __syncthreads();
    int v = cnt[t];
    off[t] = v;
    __syncthreads();
    for (int o = 1; o < 256; o <<= 1) {
        int x = (t >= o) ? off[t - o] : 0;
        __syncthreads();
        off[t] += x;
        __syncthreads();
    }
    int excl = off[t] - v;
    int node = b * 256 + t;
    if (node < n) {
        row_ptr[node] = base + excl;
        deg[node] = v;
    }
    __syncthreads();
    cnt[t] = base + excl;  // reuse as cursor
    __syncthreads();
    for (int i = t; i < m; i += 256) {
        int rec = coarse[base + i];
        int pos = atomicAdd(&cnt[rec & 255], 1);
        csr[pos] = rec >> 8;
    }
}

// ---- compute --------------------------------------------------------------

// 256 threads = 16 nodes/block, 16 lanes/node. Lane owns k-slice; x read
// direct-global (coalesced); W1 in LDS transposed wT[j][k] (stride 65 f4);
// butterfly transpose-reduce -> lane j holds h[node][j]; rows written half8.
__global__ __launch_bounds__(256) void h1_kernel(
    const float* __restrict__ x, const float* __restrict__ W1,
    const float* __restrict__ asw, const float* __restrict__ adw,
    uint4* __restrict__ h1h, float* __restrict__ as1, float* __restrict__ ad1, int n) {
    __shared__ float wT[HID * 260];   // wT[j][k], row stride 260 floats (65 f4)
    __shared__ float asv[HID], adv[HID];
    __shared__ float hstage[256];
    int t = threadIdx.x;
    {
        int jj = t & 15, kk = t >> 4;
#pragma unroll
        for (int r = 0; r < 16; ++r) {
            int k = kk + 16 * r;
            wT[jj * 260 + k] = W1[k * HID + jj];
        }
    }
    if (t < HID) { asv[t] = asw[t]; adv[t] = adw[t]; }
    __syncthreads();
    int g = t >> 4;
    int node = blockIdx.x * 16 + g;
    int lj = t & 15;
    if (node >= n) return;
    const float4* x4p = (const float4*)(x + (size_t)node * DIM);
    const float4* wT4 = (const float4*)wT;
    float acc[16];
#pragma unroll
    for (int j = 0; j < 16; ++j) acc[j] = 0.f;
#pragma unroll
    for (int s = 0; s < 4; ++s) {
        int kf = s * 16 + lj;
        float4 xv = x4p[kf];
#pragma unroll
        for (int jj = 0; jj < 16; ++jj) {
            float4 wv = wT4[jj * 65 + kf];
            acc[jj] += xv.x * wv.x + xv.y * wv.y + xv.z * wv.z + xv.w * wv.w;
        }
    }
    // butterfly transpose-reduce (compile-time register indices)
    float a8[8], a4[4], a2[2], hv;
    {
        bool p = lj & 1;
#pragma unroll
        for (int j = 0; j < 8; ++j) {
            float keep = p ? acc[2 * j + 1] : acc[2 * j];
            float send = p ? acc[2 * j] : acc[2 * j + 1];
            a8[j] = keep + __shfl_xor(send, 1, 64);
        }
    }
    {
        bool p = lj & 2;
#pragma unroll
        for (int j = 0; j < 4; ++j) {
            float keep = p ? a8[2 * j + 1] : a8[2 * j];
            float send = p ? a8[2 * j] : a8[2 * j + 1];
            a4[j] = keep + __shfl_xor(send, 2, 64);
        }
    }
    {
        bool p = lj & 4;
#pragma unroll
        for (int j = 0; j < 2; ++j) {
            float keep = p ? a4[2 * j + 1] : a4[2 * j];
            float send = p ? a4[2 * j] : a4[2 * j + 1];
            a2[j] = keep + __shfl_xor(send, 4, 64);
        }
    }
    {
        bool p = lj & 8;
        float keep = p ? a2[1] : a2[0];
        float send = p ? a2[0] : a2[1];
        hv = keep + __shfl_xor(send, 8, 64);
    }
    hstage[t] = hv;  // wave-local staging (no barrier needed within wave)
    float t1 = hv * asv[lj];
    float t2 = hv * adv[lj];
#pragma unroll
    for (int m = 1; m < 16; m <<= 1) {
        t1 += __shfl_xor(t1, m, 64);
        t2 += __shfl_xor(t2, m, 64);
    }
    if (lj == 0) { as1[node] = t1; ad1[node] = t2; }
    if (lj < 2) {
        float v8[8];
#pragma unroll
        for (int i = 0; i < 8; ++i) v8[i] = hstage[g * 16 + lj * 8 + i];
        h1h[(size_t)node * 2 + lj] = pack_half8(v8);
    }
}

// Aggregation core: 16 lanes/node = (eq 0..7 edge-slot) x (jq 0..1 row-half).
// Each lane gathers 16B (8 halves). Result acc[8]/denom valid on ALL lanes.
__device__ __forceinline__ void agg_core(
    const uint4* __restrict__ hh, const float* __restrict__ as, float adi,
    int node, int start, int cnt, const int* __restrict__ csr,
    int lg, int eq, int jq, int gbase, float* acc, float& denomv) {
    float w0 = __expf(lrelu(as[node] + adi));
    float w0s = (eq == 0) ? w0 : 0.f;
    float hs[8];
    unpack_half8(hh[(size_t)node * 2 + jq], hs);
#pragma unroll
    for (int i = 0; i < 8; ++i) acc[i] = w0s * hs[i];
    float denom = w0s;
    for (int q0 = 0; q0 < cnt; q0 += 16) {
        int myq = q0 + lg;
        int sv = 0;
        float wv = 0.f;
        if (myq < cnt) {
            sv = csr[start + myq];
            wv = __expf(lrelu(as[sv] + adi));
        }
#pragma unroll
        for (int r = 0; r < 2; ++r) {
            int lane = gbase + r * 8 + eq;
            int s = __shfl(sv, lane, 64);
            float w = __shfl(wv, lane, 64);
            denom += w;
            float hf[8];
            unpack_half8(hh[(size_t)s * 2 + jq], hf);
#pragma unroll
            for (int i = 0; i < 8; ++i) acc[i] += w * hf[i];
        }
    }
    // reduce across eq (lane bits 1..3 within group)
#pragma unroll
    for (int m = 2; m <= 8; m <<= 1) {
#pragma unroll
        for (int i = 0; i < 8; ++i) acc[i] += __shfl_xor(acc[i], m, 64);
        denom += __shfl_xor(denom, m, 64);
    }
    denomv = denom;
}

// Layer-1 aggregation: +b1, relu, write hrelu (half8), alpha2 logits via vsd.
__global__ __launch_bounds__(256) void agg1_kernel(
    const uint4* __restrict__ hh, const float* __restrict__ as, const float* __restrict__ ad,
    const int* __restrict__ row_ptr, const int* __restrict__ deg, const int* __restrict__ csr,
    const float* __restrict__ bias, const float* __restrict__ vsd,
    uint4* __restrict__ outh, float* __restrict__ as_out, float* __restrict__ ad_out,
    int n) {
    int t = threadIdx.x;
    int node = blockIdx.x * 16 + (t >> 4);
    if (node >= n) return;
    int lg = t & 15, jq = lg & 1, eq = lg >> 1, gbase = t & 48;
    float adi = ad[node];
    float acc[8];
    float denom;
    agg_core(hh, as, adi, node, row_ptr[node], deg[node], csr, lg, eq, jq, gbase, acc, denom);
    float inv = 1.f / denom;
    const float* bj = bias + jq * 8;
    float val[8];
#pragma unroll
    for (int i = 0; i < 8; ++i) val[i] = fmaxf(acc[i] * inv + bj[i], 0.f);
    if (eq == 0) outh[(size_t)node * 2 + jq] = pack_half8(val);
    const float* vs = vsd + jq * 8;
    const float* vd = vsd + 16 + jq * 8;
    float t1 = 0.f, t2 = 0.f;
#pragma unroll
    for (int i = 0; i < 8; ++i) { t1 += val[i] * vs[i]; t2 += val[i] * vd[i]; }
    t1 += __shfl_xor(t1, 1, 64);
    t2 += __shfl_xor(t2, 1, 64);
    if (lg == 0) { as_out[node] = t1; ad_out[node] = t2; }
}

// Layer-2 aggregation fused with @W2 + b2 + log_softmax.
__global__ __launch_bounds__(256) void agg2_final_kernel(
    const uint4* __restrict__ hh, const float* __restrict__ as, const float* __restrict__ ad,
    const int* __restrict__ row_ptr, const int* __restrict__ deg, const int* __restrict__ csr,
    const float* __restrict__ W2, const float* __restrict__ b2,
    float* __restrict__ out, int n) {
    __shared__ float a2s[16 * HID];       // staged agg rows for this block
    __shared__ float w2s[HID * NCLS];     // 4KB
    __shared__ float b2s[NCLS];
    int t = threadIdx.x;
    for (int i = t; i < HID * NCLS; i += 256) w2s[i] = W2[i];
    if (t < NCLS) b2s[t] = b2[t];
    int g = t >> 4;
    int node = blockIdx.x * 16 + g;
    int lg = t & 15, jq = lg & 1, eq = lg >> 1, gbase = t & 48;
    if (node < n) {
        float adi = ad[node];
        float acc[8];
        float denom;
        agg_core(hh, as, adi, node, row_ptr[node], deg[node], csr, lg, eq, jq, gbase, acc, denom);
        float inv = 1.f / denom;
        if (eq == 0) {
            float* dst = &a2s[g * HID + jq * 8];
            *(float4*)dst = make_float4(acc[0] * inv, acc[1] * inv, acc[2] * inv, acc[3] * inv);
            *(float4*)(dst + 4) = make_float4(acc[4] * inv, acc[5] * inv, acc[6] * inv, acc[7] * inv);
        }
    }
    __syncthreads();
    int wv = t >> 6;   // wave id 0..3
    int c = t & 63;
#pragma unroll
    for (int i = 0; i < 4; ++i) {
        int nl = i * 4 + wv;
        int gn = blockIdx.x * 16 + nl;
        if (gn >= n) continue;
        const float* ar = &a2s[nl * HID];
        float v = b2s[c];
#pragma unroll
        for (int j = 0; j < HID; ++j) v += ar[j] * w2s[j * NCLS + c];
        float mx = v;
#pragma unroll
        for (int off = 1; off < 64; off <<= 1) mx = fmaxf(mx, __shfl_xor(mx, off, 64));
        float ex = __expf(v - mx);
        float s = ex;
#pragma unroll
        for (int off = 1; off < 64; off <<= 1) s += __shfl_xor(s, off, 64);
        out[(size_t)gn * NCLS + c] = (v - mx) - __logf(s);
    }
}

extern "C" void kernel_launch(void* const* d_in, const int* in_sizes, int n_in,
                              void* d_out, int out_size, void* d_ws, size_t ws_size,
                              hipStream_t stream) {
    const float* x    = (const float*)d_in[0];
    const int*   ei   = (const int*)d_in[1];  // [2,E]: [0..E)=src, [E..2E)=dst
    const float* W1   = (const float*)d_in[2];
    const float* a_s1 = (const float*)d_in[3];
    const float* a_d1 = (const float*)d_in[4];
    const float* b1   = (const float*)d_in[5];
    const float* W2   = (const float*)d_in[6];
    const float* a_s2 = (const float*)d_in[7];
    const float* a_d2 = (const float*)d_in[8];
    const float* b2   = (const float*)d_in[9];
    float* out = (float*)d_out;

    const int N = in_sizes[0] / DIM;
    const int E = in_sizes[1] / 2;
    const int NB = (N + 255) >> 8;  // buckets of 256 dst nodes (<= 512)

    char* p = (char*)d_ws;
    auto alloc = [&](size_t bytes) {
        char* r = p;
        p += (bytes + 255) & ~(size_t)255;
        return r;
    };
    int*   bkt_cnt  = (int*)alloc(512 * 4);
    int*   bkt_base = (int*)alloc(512 * 4);
    int*   bkt_cur  = (int*)alloc(512 * 4);
    int*   coarse   = (int*)alloc((size_t)E * 4);
    int*   csr      = (int*)alloc((size_t)E * 4);
    int*   row_ptr  = (int*)alloc((size_t)N * 4);
    int*   deg      = (int*)alloc((size_t)N * 4);
    float* as1      = (float*)alloc((size_t)N * 4);
    float* ad1      = (float*)alloc((size_t)N * 4);
    float* as2      = (float*)alloc((size_t)N * 4);
    float* ad2      = (float*)alloc((size_t)N * 4);
    float* vsd      = (float*)alloc(32 * 4);
    // coarse (12.8MB) is dead after p2_fine; half8 h-tables alias onto it
    // (2 tables x N x 32B = 6.4MB).
    uint4* h1h    = (uint4*)coarse;
    uint4* hreluh = h1h + (size_t)N * 2;

    const int nblkE = (E + P1_CHUNK - 1) / P1_CHUNK;

    vsd_kernel<<<1, 512, 0, stream>>>(W2, a_s2, a_d2, vsd, bkt_cnt);
    p0_hist<<<nblkE, 256, 0, stream>>>(ei + E, E, bkt_cnt);
    scanb<<<1, 512, 0, stream>>>(bkt_cnt, bkt_base, bkt_cur, NB);
    p1_scatter<<<nblkE, 256, 0, stream>>>(ei, E, bkt_cur, coarse);
    p2_fine<<<NB, 256, 0, stream>>>(coarse, bkt_base, bkt_cnt, csr, row_ptr, deg, N);
    h1_kernel<<<(N + 15) / 16, 256, 0, stream>>>(x, W1, a_s1, a_d1, h1h, as1, ad1, N);
    agg1_kernel<<<(N + 15) / 16, 256, 0, stream>>>(h1h, as1, ad1, row_ptr, deg, csr,
                                                   b1, vsd, hreluh, as2, ad2, N);
    agg2_final_kernel<<<(N + 15) / 16, 256, 0, stream>>>(hreluh, as2, ad2, row_ptr, deg, csr,
                                                         W2, b2, out, N);
}

// Round 7
// 345.871 us; speedup vs baseline: 1.1990x; 1.0675x over previous
//
#include <hip/hip_runtime.h>
#include <hip/hip_fp16.h>

// GAT 2-layer, N=100K, DIM=256, HID=16, NCLS=64, E=3.2M (+N self loops).
//  - CSR build: two-level bucketed counting sort. p2 sorts into LDS (CAP
//    8704 >= max bucket ~8500 for Poisson(8192); fallback path keeps
//    correctness unconditionally) then writes csr coalesced.
//  - h1 = x@W1 via MFMA f16 (16x16x32): wave = 16-node tile, A = x rows
//    direct-global fp32->f16, B = W1^T frags in registers (8 K-steps).
//    A/B use the same (lane,i)->k convention so any HW k-permutation
//    cancels; C/D layout col=lane&15,row=(lane>>4)*4+reg (HW-verified).
//    FUSED into p1's dispatch (independent work, disjoint block ranges,
//    union'd LDS) to overlap MFMA/VMEM work with p1's scatter.
//  - agg: 16 lanes/node = (eq 0..7) x (jq 0..1 half-row), uint4 fp16 row
//    gathers, no-max softmax (max cancels algebraically).
//  - layer2 fused: (sum a*h_relu)@W2 == sum a*(h_relu@W2); @W2 + b2 +
//    log_softmax in-block (no h2 round-trip).

#define DIM 256
#define HID 16
#define NCLS 64
#define NEG 0.2f
#define P1_CHUNK 4096
#define CAP 8704

typedef _Float16 f16x8 __attribute__((ext_vector_type(8)));
typedef float f32x4 __attribute__((ext_vector_type(4)));

__device__ __forceinline__ float lrelu(float v) { return v >= 0.f ? v : NEG * v; }

__device__ __forceinline__ uint4 pack_half8(const float* v) {
    __half2 p0 = __floats2half2_rn(v[0], v[1]);
    __half2 p1 = __floats2half2_rn(v[2], v[3]);
    __half2 p2 = __floats2half2_rn(v[4], v[5]);
    __half2 p3 = __floats2half2_rn(v[6], v[7]);
    return make_uint4(*(unsigned*)&p0, *(unsigned*)&p1, *(unsigned*)&p2, *(unsigned*)&p3);
}

__device__ __forceinline__ void unpack_half8(uint4 u, float* f) {
    float2 f0 = __half22float2(*(__half2*)&u.x);
    float2 f1 = __half22float2(*(__half2*)&u.y);
    float2 f2 = __half22float2(*(__half2*)&u.z);
    float2 f3 = __half22float2(*(__half2*)&u.w);
    f[0] = f0.x; f[1] = f0.y; f[2] = f1.x; f[3] = f1.y;
    f[4] = f2.x; f[5] = f2.y; f[6] = f3.x; f[7] = f3.y;
}

// Also zeroes bkt_cnt (replaces a separate memset dispatch).
__global__ void vsd_kernel(const float* __restrict__ W2, const float* __restrict__ as2,
                           const float* __restrict__ ad2, float* __restrict__ vsd,
                           int* __restrict__ bkt_cnt) {
    int t = threadIdx.x;
    bkt_cnt[t] = 0;  // 512 threads
    if (t < 32) {
        int j = t & 15;
        const float* a = (t < 16) ? as2 : ad2;
        float s = 0.f;
        for (int c = 0; c < NCLS; ++c) s += W2[j * NCLS + c] * a[c];
        vsd[t] = s;
    }
}

// ---- CSR build ------------------------------------------------------------

__global__ __launch_bounds__(256) void p0_hist(const int* __restrict__ dst, int E,
                                               int* __restrict__ bkt_cnt) {
    __shared__ int hist[512];
    int t = threadIdx.x;
    for (int i = t; i < 512; i += 256) hist[i] = 0;
    __syncthreads();
    int base = blockIdx.x * P1_CHUNK;
    for (int k = 0; k < 16; ++k) {
        int idx = base + k * 256 + t;
        if (idx < E) atomicAdd(&hist[dst[idx] >> 8], 1);
    }
    __syncthreads();
    for (int i = t; i < 512; i += 256)
        if (hist[i]) atomicAdd(&bkt_cnt[i], hist[i]);
}

__global__ void scanb(const int* __restrict__ bkt_cnt, int* __restrict__ bkt_base,
                      int* __restrict__ bkt_cur, int nb) {
    __shared__ int lds[512];
    int t = threadIdx.x;
    int v = (t < nb) ? bkt_cnt[t] : 0;
    lds[t] = v;
    __syncthreads();
    for (int o = 1; o < 512; o <<= 1) {
        int x = (t >= o) ? lds[t - o] : 0;
        __syncthreads();
        lds[t] += x;
        __syncthreads();
    }
    if (t < nb) {
        int e = lds[t] - v;
        bkt_base[t] = e;
        bkt_cur[t] = e;
    }
}

// Fused p1_scatter + h1 MFMA (independent work, disjoint block ranges).
struct P1S {
    int hist[512];
    int recs[P1_CHUNK];
    unsigned short bkts[P1_CHUNK];
};
struct H1S {
    _Float16 w1t[16][264];    // W1^T f16, padded row stride (528B, 16B-mult)
    _Float16 hst[4][16][16];  // per-wave row staging for packed writeout
};

__global__ __launch_bounds__(256) void p1h1_kernel(
    const int* __restrict__ ei, int E, int* __restrict__ bkt_cur,
    int* __restrict__ coarse, int nblkE,
    const float* __restrict__ x, const float* __restrict__ W1,
    const float* __restrict__ asw, const float* __restrict__ adw,
    uint4* __restrict__ h1h, float* __restrict__ as1, float* __restrict__ ad1, int n) {
    __shared__ union __align__(16) { P1S p1; H1S h1; } sm;
    int t = threadIdx.x;
    if ((int)blockIdx.x < nblkE) {
        // ---------------- p1 scatter ----------------
        int base = blockIdx.x * P1_CHUNK;
        for (int i = t; i < 512; i += 256) sm.p1.hist[i] = 0;
        __syncthreads();
        for (int k = 0; k < 16; ++k) {
            int idx = base + k * 256 + t;
            int li = k * 256 + t;
            if (idx < E) {
                int s = ei[idx];
                int d = ei[E + idx];
                int bk = d >> 8;
                sm.p1.recs[li] = (s << 8) | (d & 255);
                sm.p1.bkts[li] = (unsigned short)bk;
                atomicAdd(&sm.p1.hist[bk], 1);
            } else {
                sm.p1.bkts[li] = 0xFFFF;
            }
        }
        __syncthreads();
        for (int b = t; b < 512; b += 256) {
            int c = sm.p1.hist[b];
            sm.p1.hist[b] = c ? atomicAdd(&bkt_cur[b], c) : 0;
        }
        __syncthreads();
        for (int k = 0; k < 16; ++k) {
            int li = k * 256 + t;
            unsigned short bk = sm.p1.bkts[li];
            if (bk != 0xFFFF) {
                int pos = atomicAdd(&sm.p1.hist[bk], 1);
                coarse[pos] = sm.p1.recs[li];
            }
        }
    } else {
        // ---------------- h1 MFMA ----------------
        int hb = blockIdx.x - nblkE;
        {
            const float* row = W1 + t * HID;  // t = k index 0..255
#pragma unroll
            for (int nn2 = 0; nn2 < 16; ++nn2)
                sm.h1.w1t[nn2][t] = (_Float16)row[nn2];
        }
        __syncthreads();
        int lane = t & 63, wave = t >> 6;
        int q = lane >> 4, nn = lane & 15;
        f16x8 bfrag[8];
#pragma unroll
        for (int s = 0; s < 8; ++s) {
            int kb = s * 32 + q * 8;
            bfrag[s] = *(const f16x8*)&sm.h1.w1t[nn][kb];
        }
        float asv = asw[nn], adv = adw[nn];
#pragma unroll
        for (int it = 0; it < 4; ++it) {
            int nb = hb * 256 + wave * 64 + it * 16;
            if (nb >= n) break;
            int node = nb + nn;
            const float* xr = x + (size_t)min(node, n - 1) * DIM;
            f32x4 acc = {0.f, 0.f, 0.f, 0.f};
#pragma unroll
            for (int s = 0; s < 8; ++s) {
                int kb = s * 32 + q * 8;
                float4 xa = *(const float4*)(xr + kb);
                float4 xb = *(const float4*)(xr + kb + 4);
                f16x8 af;
                af[0] = (_Float16)xa.x; af[1] = (_Float16)xa.y;
                af[2] = (_Float16)xa.z; af[3] = (_Float16)xa.w;
                af[4] = (_Float16)xb.x; af[5] = (_Float16)xb.y;
                af[6] = (_Float16)xb.z; af[7] = (_Float16)xb.w;
                acc = __builtin_amdgcn_mfma_f32_16x16x32_f16(af, bfrag[s], acc, 0, 0, 0);
            }
            // D[row=q*4+r][col=nn]; row = node-in-tile, col = j.
#pragma unroll
            for (int r = 0; r < 4; ++r) {
                float v = acc[r];
                sm.h1.hst[wave][q * 4 + r][nn] = (_Float16)v;
                float t1 = v * asv, t2 = v * adv;
#pragma unroll
                for (int mm = 1; mm < 16; mm <<= 1) {
                    t1 += __shfl_xor(t1, mm, 64);
                    t2 += __shfl_xor(t2, mm, 64);
                }
                if (nn == 0) {
                    int nd = nb + q * 4 + r;
                    if (nd < n) { as1[nd] = t1; ad1[nd] = t2; }
                }
            }
            __builtin_amdgcn_s_waitcnt(0);  // drain ds_writes (wave-lockstep)
            if (lane < 32) {
                int nl = lane >> 1, jq = lane & 1;
                int nd = nb + nl;
                if (nd < n)
                    h1h[(size_t)nd * 2 + jq] = *(const uint4*)&sm.h1.hst[wave][nl][jq * 8];
            }
        }
    }
}

// p2: per-bucket fine sort staged in LDS -> coalesced csr writeout.
__global__ __launch_bounds__(256) void p2_fine(const int* __restrict__ coarse,
                                               const int* __restrict__ bkt_base,
                                               const int* __restrict__ bkt_cnt,
                                               int* __restrict__ csr, int* __restrict__ row_ptr,
                                               int* __restrict__ deg, int n) {
    __shared__ int cnt[256];
    __shared__ int off[256];
    __shared__ int csr_loc[CAP];
    int b = blockIdx.x;
    int t = threadIdx.x;
    cnt[t] = 0;
    __syncthreads();
    int base = bkt_base[b];
    int m = bkt_cnt[b];
    for (int i = t; i < m; i += 256) atomicAdd(&cnt[coarse[base + i] & 255], 1);
    __syncthreads();
    int v = cnt[t];
    off[t] = v;
    __syncthreads();
    for (int o = 1; o < 256; o <<= 1) {
        int xg = (t >= o) ? off[t - o] : 0;
        __syncthreads();
        off[t] += xg;
        __syncthreads();
    }
    int excl = off[t] - v;
    int node = b * 256 + t;
    if (node < n) {
        row_ptr[node] = base + excl;
        deg[node] = v;
    }
    __syncthreads();
    cnt[t] = excl;  // local cursor
    __syncthreads();
    if (m <= CAP) {
        for (int i = t; i < m; i += 256) {
            int rec = coarse[base + i];
            int pos = atomicAdd(&cnt[rec & 255], 1);
            csr_loc[pos] = rec >> 8;
        }
        __syncthreads();
        for (int i = t; i < m; i += 256) csr[base + i] = csr_loc[i];
    } else {  // never expected; correctness fallback
        for (int i = t; i < m; i += 256) {
            int rec = coarse[base + i];
            int pos = atomicAdd(&cnt[rec & 255], 1);
            csr[base + pos] = rec >> 8;
        }
    }
}

// ---- aggregation ----------------------------------------------------------

// 16 lanes/node = (eq 0..7 edge-slot) x (jq 0..1 row-half); uint4 gathers.
__device__ __forceinline__ void agg_core(
    const uint4* __restrict__ hh, const float* __restrict__ as, float adi,
    int node, int start, int cnt, const int* __restrict__ csr,
    int lg, int eq, int jq, int gbase, float* acc, float& denomv) {
    float w0 = __expf(lrelu(as[node] + adi));
    float w0s = (eq == 0) ? w0 : 0.f;
    float hs[8];
    unpack_half8(hh[(size_t)node * 2 + jq], hs);
#pragma unroll
    for (int i = 0; i < 8; ++i) acc[i] = w0s * hs[i];
    float denom = w0s;
    for (int q0 = 0; q0 < cnt; q0 += 16) {
        int myq = q0 + lg;
        int sv = 0;
        float wv = 0.f;
        if (myq < cnt) {
            sv = csr[start + myq];
            wv = __expf(lrelu(as[sv] + adi));
        }
#pragma unroll
        for (int r = 0; r < 2; ++r) {
            int lane = gbase + r * 8 + eq;
            int s = __shfl(sv, lane, 64);
            float w = __shfl(wv, lane, 64);
            denom += w;
            float hf[8];
            unpack_half8(hh[(size_t)s * 2 + jq], hf);
#pragma unroll
            for (int i = 0; i < 8; ++i) acc[i] += w * hf[i];
        }
    }
#pragma unroll
    for (int m = 2; m <= 8; m <<= 1) {
#pragma unroll
        for (int i = 0; i < 8; ++i) acc[i] += __shfl_xor(acc[i], m, 64);
        denom += __shfl_xor(denom, m, 64);
    }
    denomv = denom;
}

__global__ __launch_bounds__(256) void agg1_kernel(
    const uint4* __restrict__ hh, const float* __restrict__ as, const float* __restrict__ ad,
    const int* __restrict__ row_ptr, const int* __restrict__ deg, const int* __restrict__ csr,
    const float* __restrict__ bias, const float* __restrict__ vsd,
    uint4* __restrict__ outh, float* __restrict__ as_out, float* __restrict__ ad_out,
    int n) {
    int t = threadIdx.x;
    int node = blockIdx.x * 16 + (t >> 4);
    if (node >= n) return;
    int lg = t & 15, jq = lg & 1, eq = lg >> 1, gbase = t & 48;
    float adi = ad[node];
    float acc[8];
    float denom;
    agg_core(hh, as, adi, node, row_ptr[node], deg[node], csr, lg, eq, jq, gbase, acc, denom);
    float inv = 1.f / denom;
    const float* bj = bias + jq * 8;
    float val[8];
#pragma unroll
    for (int i = 0; i < 8; ++i) val[i] = fmaxf(acc[i] * inv + bj[i], 0.f);
    if (eq == 0) outh[(size_t)node * 2 + jq] = pack_half8(val);
    const float* vs = vsd + jq * 8;
    const float* vd = vsd + 16 + jq * 8;
    float t1 = 0.f, t2 = 0.f;
#pragma unroll
    for (int i = 0; i < 8; ++i) { t1 += val[i] * vs[i]; t2 += val[i] * vd[i]; }
    t1 += __shfl_xor(t1, 1, 64);
    t2 += __shfl_xor(t2, 1, 64);
    if (lg == 0) { as_out[node] = t1; ad_out[node] = t2; }
}

__global__ __launch_bounds__(256) void agg2_final_kernel(
    const uint4* __restrict__ hh, const float* __restrict__ as, const float* __restrict__ ad,
    const int* __restrict__ row_ptr, const int* __restrict__ deg, const int* __restrict__ csr,
    const float* __restrict__ W2, const float* __restrict__ b2,
    float* __restrict__ out, int n) {
    __shared__ float a2s[16 * HID];
    __shared__ float w2s[HID * NCLS];
    __shared__ float b2s[NCLS];
    int t = threadIdx.x;
    for (int i = t; i < HID * NCLS; i += 256) w2s[i] = W2[i];
    if (t < NCLS) b2s[t] = b2[t];
    int g = t >> 4;
    int node = blockIdx.x * 16 + g;
    int lg = t & 15, jq = lg & 1, eq = lg >> 1, gbase = t & 48;
    if (node < n) {
        float adi = ad[node];
        float acc[8];
        float denom;
        agg_core(hh, as, adi, node, row_ptr[node], deg[node], csr, lg, eq, jq, gbase, acc, denom);
        float inv = 1.f / denom;
        if (eq == 0) {
            float* dst = &a2s[g * HID + jq * 8];
            *(float4*)dst = make_float4(acc[0] * inv, acc[1] * inv, acc[2] * inv, acc[3] * inv);
            *(float4*)(dst + 4) = make_float4(acc[4] * inv, acc[5] * inv, acc[6] * inv, acc[7] * inv);
        }
    }
    __syncthreads();
    int wv = t >> 6;
    int c = t & 63;
#pragma unroll
    for (int i = 0; i < 4; ++i) {
        int nl = i * 4 + wv;
        int gn = blockIdx.x * 16 + nl;
        if (gn >= n) continue;
        const float* ar = &a2s[nl * HID];
        float v = b2s[c];
#pragma unroll
        for (int j = 0; j < HID; ++j) v += ar[j] * w2s[j * NCLS + c];
        float mx = v;
#pragma unroll
        for (int off = 1; off < 64; off <<= 1) mx = fmaxf(mx, __shfl_xor(mx, off, 64));
        float ex = __expf(v - mx);
        float s = ex;
#pragma unroll
        for (int off = 1; off < 64; off <<= 1) s += __shfl_xor(s, off, 64);
        out[(size_t)gn * NCLS + c] = (v - mx) - __logf(s);
    }
}

extern "C" void kernel_launch(void* const* d_in, const int* in_sizes, int n_in,
                              void* d_out, int out_size, void* d_ws, size_t ws_size,
                              hipStream_t stream) {
    const float* x    = (const float*)d_in[0];
    const int*   ei   = (const int*)d_in[1];  // [2,E]: [0..E)=src, [E..2E)=dst
    const float* W1   = (const float*)d_in[2];
    const float* a_s1 = (const float*)d_in[3];
    const float* a_d1 = (const float*)d_in[4];
    const float* b1   = (const float*)d_in[5];
    const float* W2   = (const float*)d_in[6];
    const float* a_s2 = (const float*)d_in[7];
    const float* a_d2 = (const float*)d_in[8];
    const float* b2   = (const float*)d_in[9];
    float* out = (float*)d_out;

    const int N = in_sizes[0] / DIM;
    const int E = in_sizes[1] / 2;
    const int NB = (N + 255) >> 8;

    char* p = (char*)d_ws;
    auto alloc = [&](size_t bytes) {
        char* r = p;
        p += (bytes + 255) & ~(size_t)255;
        return r;
    };
    int*   bkt_cnt  = (int*)alloc(512 * 4);
    int*   bkt_base = (int*)alloc(512 * 4);
    int*   bkt_cur  = (int*)alloc(512 * 4);
    int*   coarse   = (int*)alloc((size_t)E * 4);
    int*   csr      = (int*)alloc((size_t)E * 4);
    int*   row_ptr  = (int*)alloc((size_t)N * 4);
    int*   deg      = (int*)alloc((size_t)N * 4);
    float* as1      = (float*)alloc((size_t)N * 4);
    float* ad1      = (float*)alloc((size_t)N * 4);
    float* as2      = (float*)alloc((size_t)N * 4);
    float* ad2      = (float*)alloc((size_t)N * 4);
    float* vsd      = (float*)alloc(32 * 4);
    // h tables NOT aliased onto coarse anymore: h1 runs fused with p1
    // (which writes coarse concurrently).
    uint4* h1h    = (uint4*)alloc((size_t)N * 32);
    uint4* hreluh = (uint4*)alloc((size_t)N * 32);

    const int nblkE = (E + P1_CHUNK - 1) / P1_CHUNK;
    const int h1blk = (N + 255) / 256;

    vsd_kernel<<<1, 512, 0, stream>>>(W2, a_s2, a_d2, vsd, bkt_cnt);
    p0_hist<<<nblkE, 256, 0, stream>>>(ei + E, E, bkt_cnt);
    scanb<<<1, 512, 0, stream>>>(bkt_cnt, bkt_base, bkt_cur, NB);
    p1h1_kernel<<<nblkE + h1blk, 256, 0, stream>>>(ei, E, bkt_cur, coarse, nblkE,
                                                   x, W1, a_s1, a_d1, h1h, as1, ad1, N);
    p2_fine<<<NB, 256, 0, stream>>>(coarse, bkt_base, bkt_cnt, csr, row_ptr, deg, N);
    agg1_kernel<<<(N + 15) / 16, 256, 0, stream>>>(h1h, as1, ad1, row_ptr, deg, csr,
                                                   b1, vsd, hreluh, as2, ad2, N);
    agg2_final_kernel<<<(N + 15) / 16, 256, 0, stream>>>(hreluh, as2, ad2, row_ptr, deg, csr,
                                                         W2, b2, out, N);
}